// Round 5
// baseline (412.447 us; speedup 1.0000x reference)
//
#include <hip/hip_runtime.h>

// Problem constants: B=16, NH=8, DH=64, NG=4, NC=512, CG=128, GH=2, H=W=32,
// HW=1024, Hs=Ws=16, NS=256, scale=0.125, ORF*off_range = 2/15.
// DT template param: 0 = buffers are bf16, 1 = buffers are fp32 (runtime-probed).

typedef __attribute__((ext_vector_type(8))) short short8;
typedef __attribute__((ext_vector_type(4))) float f32x4;

__device__ __forceinline__ float bf2f(ushort u) {
    union { uint i; float f; } c; c.i = ((uint)u) << 16; return c.f;
}
__device__ __forceinline__ ushort f2bf(float f) {
    union { float f; uint i; } c; c.f = f;
    uint x = c.i;
    return (ushort)((x + 0x7fffu + ((x >> 16) & 1u)) >> 16);  // RNE
}
__device__ __forceinline__ float sat(float v, float lim) {
    return fminf(fmaxf(v, -lim), lim);  // also flushes NaN -> -lim
}
template <int DT> __device__ __forceinline__ float ldv(const void* p, size_t i) {
    return DT ? ((const float*)p)[i] : bf2f(((const ushort*)p)[i]);
}
template <int DT> __device__ __forceinline__ void stv(void* p, size_t i, float v) {
    if (DT) ((float*)p)[i] = v; else ((ushort*)p)[i] = f2bf(v);
}
// load 8 consecutive elements (i % 8 == 0) converted to bf16 -> dst[0..7]
template <int DT> __device__ __forceinline__ void ld8bf(ushort* dst, const void* p, size_t i) {
    if (DT) {
        float4 f0 = ((const float4*)p)[i / 4];
        float4 f1 = ((const float4*)p)[i / 4 + 1];
        dst[0] = f2bf(f0.x); dst[1] = f2bf(f0.y); dst[2] = f2bf(f0.z); dst[3] = f2bf(f0.w);
        dst[4] = f2bf(f1.x); dst[5] = f2bf(f1.y); dst[6] = f2bf(f1.z); dst[7] = f2bf(f1.w);
    } else {
        *(uint4*)dst = *(const uint4*)((const ushort*)p + i);
    }
}
__device__ __forceinline__ f32x4 mfma_bf16(short8 a, short8 b, f32x4 c) {
    return __builtin_amdgcn_mfma_f32_16x16x32_bf16(a, b, c, 0, 0, 0);
}

// ---------------------------------------------------------------------------
// Dtype probe: even-indexed 16-bit halves of Wq decode to plausible bf16
// (~0.02 magnitude) iff the buffer is bf16. fp32 low mantissa halves: ~6% hit.
__global__ void dtype_probe(const void* wq, int* flag) {
    __shared__ int sh[64];
    int t = threadIdx.x;
    int cnt = 0;
    for (int k = 0; k < 4; k++) {
        ushort u = ((const ushort*)wq)[(size_t)(t * 4 + k) * 2];
        float v = fabsf(bf2f(u));
        cnt += (v > 1e-5f && v < 0.5f) ? 1 : 0;
    }
    sh[t] = cnt;
    __syncthreads();
    for (int s = 32; s; s >>= 1) { if (t < s) sh[t] += sh[t + s]; __syncthreads(); }
    if (t == 0) flag[0] = (sh[0] >= 128) ? 0 : 1;
}

// ---------------------------------------------------------------------------
// q = Wq*x + bq -> qT[bl][hw][c] (chunk-local, internal bf16).
// X per global batch [512][1024]; staged transposed into LDS.
template <int DT>
__global__ __launch_bounds__(256) void gemm_qx(const void* __restrict__ A,
                                               const void* __restrict__ X,
                                               const void* __restrict__ bias,
                                               ushort* __restrict__ C,
                                               const int* __restrict__ flag, int b0) {
    if (flag[0] != DT) return;
    __shared__ __align__(16) ushort As[64][72];
    __shared__ __align__(16) ushort Bs[64][72];
    int bl = blockIdx.z, bg = b0 + bl, m0 = blockIdx.y * 64, n0 = blockIdx.x * 64;
    size_t xbase = (size_t)bg * 512 * 1024;
    ushort* Cp = C + (size_t)bl * 1024 * 512;
    int t = threadIdx.x, w = t >> 6, lane = t & 63, col = lane & 15, quad = lane >> 4;
    int m_off = (w & 1) * 32, n_off = (w >> 1) * 32;
    f32x4 acc[2][2] = {};
    for (int k0 = 0; k0 < 512; k0 += 64) {
        __syncthreads();
        for (int i = t; i < 512; i += 256) {
            int r = i >> 3, c8 = (i & 7) * 8;
            ld8bf<DT>(&As[r][c8], A, (size_t)(m0 + r) * 512 + k0 + c8);
            ushort tmp[8];
            ld8bf<DT>(tmp, X, xbase + (size_t)(k0 + r) * 1024 + n0 + c8);
#pragma unroll
            for (int j = 0; j < 8; j++) Bs[c8 + j][r] = tmp[j];
        }
        __syncthreads();
#pragma unroll
        for (int kk = 0; kk < 2; kk++) {
            short8 a0 = *(const short8*)&As[m_off + col][kk * 32 + quad * 8];
            short8 a1 = *(const short8*)&As[m_off + 16 + col][kk * 32 + quad * 8];
            short8 b0v = *(const short8*)&Bs[n_off + col][kk * 32 + quad * 8];
            short8 b1v = *(const short8*)&Bs[n_off + 16 + col][kk * 32 + quad * 8];
            acc[0][0] = mfma_bf16(a0, b0v, acc[0][0]);
            acc[0][1] = mfma_bf16(a0, b1v, acc[0][1]);
            acc[1][0] = mfma_bf16(a1, b0v, acc[1][0]);
            acc[1][1] = mfma_bf16(a1, b1v, acc[1][1]);
        }
    }
#pragma unroll
    for (int mi = 0; mi < 2; mi++)
#pragma unroll
        for (int ni = 0; ni < 2; ni++) {
            int mg = m0 + m_off + mi * 16 + quad * 4;
            int ng = n0 + n_off + ni * 16 + col;
            f32x4 vv = acc[mi][ni];
            ushort4 pk;
            pk.x = f2bf(sat(vv[0] + ldv<DT>(bias, mg + 0), 1e4f));
            pk.y = f2bf(sat(vv[1] + ldv<DT>(bias, mg + 1), 1e4f));
            pk.z = f2bf(sat(vv[2] + ldv<DT>(bias, mg + 2), 1e4f));
            pk.w = f2bf(sat(vv[3] + ldv<DT>(bias, mg + 3), 1e4f));
            *(ushort4*)&Cp[(size_t)ng * 512 + mg] = pk;
        }
}

// ---------------------------------------------------------------------------
// C[m][n] = sum_k A[m][k]*B[n][k] + bias[m]. A dtype DT, B internal bf16.
// OUT_T=1: packed C^T bf16 (internal). OUT_T=0 + CINT=1: bf16 internal;
// CINT=0: dtype-DT store to c0 + b*sC + m*ldc + n.
template <int OUT_T, int DT, int CINT>
__global__ __launch_bounds__(256) void gemm_tn(const void* __restrict__ A,
                                               const ushort* __restrict__ Bm,
                                               const void* __restrict__ bias,
                                               void* __restrict__ C,
                                               const int* __restrict__ flag, int K,
                                               size_t sB, size_t sC, int ldc, size_t c0) {
    if (flag[0] != DT) return;
    __shared__ __align__(16) ushort As[64][72];
    __shared__ __align__(16) ushort Bs[64][72];
    int b = blockIdx.z, m0 = blockIdx.y * 64, n0 = blockIdx.x * 64;
    const ushort* Bp = Bm + (size_t)b * sB;
    size_t cb = c0 + (size_t)b * sC;
    int t = threadIdx.x, w = t >> 6, lane = t & 63, col = lane & 15, quad = lane >> 4;
    int m_off = (w & 1) * 32, n_off = (w >> 1) * 32;
    f32x4 acc[2][2] = {};
    for (int k0 = 0; k0 < K; k0 += 64) {
        __syncthreads();
        for (int i = t; i < 512; i += 256) {
            int r = i >> 3, c8 = (i & 7) * 8;
            ld8bf<DT>(&As[r][c8], A, (size_t)(m0 + r) * K + k0 + c8);
            *(uint4*)&Bs[r][c8] = *(const uint4*)&Bp[(size_t)(n0 + r) * K + k0 + c8];
        }
        __syncthreads();
#pragma unroll
        for (int kk = 0; kk < 2; kk++) {
            short8 a0 = *(const short8*)&As[m_off + col][kk * 32 + quad * 8];
            short8 a1 = *(const short8*)&As[m_off + 16 + col][kk * 32 + quad * 8];
            short8 b0v = *(const short8*)&Bs[n_off + col][kk * 32 + quad * 8];
            short8 b1v = *(const short8*)&Bs[n_off + 16 + col][kk * 32 + quad * 8];
            acc[0][0] = mfma_bf16(a0, b0v, acc[0][0]);
            acc[0][1] = mfma_bf16(a0, b1v, acc[0][1]);
            acc[1][0] = mfma_bf16(a1, b0v, acc[1][0]);
            acc[1][1] = mfma_bf16(a1, b1v, acc[1][1]);
        }
    }
#pragma unroll
    for (int mi = 0; mi < 2; mi++)
#pragma unroll
        for (int ni = 0; ni < 2; ni++) {
            int mg = m0 + m_off + mi * 16 + quad * 4;
            int ng = n0 + n_off + ni * 16 + col;
            f32x4 vv = acc[mi][ni];
            if (OUT_T == 1) {
                ushort4 pk;
                pk.x = f2bf(sat(vv[0] + ldv<DT>(bias, mg + 0), 1e4f));
                pk.y = f2bf(sat(vv[1] + ldv<DT>(bias, mg + 1), 1e4f));
                pk.z = f2bf(sat(vv[2] + ldv<DT>(bias, mg + 2), 1e4f));
                pk.w = f2bf(sat(vv[3] + ldv<DT>(bias, mg + 3), 1e4f));
                *(ushort4*)&((ushort*)C)[cb + (size_t)ng * ldc + mg] = pk;
            } else {
#pragma unroll
                for (int r = 0; r < 4; r++) {
                    float v = sat(vv[r] + ldv<DT>(bias, mg + r), 1e4f);
                    if (CINT) ((ushort*)C)[cb + (size_t)(mg + r) * ldc + ng] = f2bf(v);
                    else stv<DT>(C, cb + (size_t)(mg + r) * ldc + ng, v);
                }
            }
        }
}

// ---------------------------------------------------------------------------
// Offset network: depthwise 3x3 s2 p1 -> LN(channel) -> GELU -> 1x1 -> tanh*2/15.
// pos (fp32, chunk-local ws) + pos/ref outputs (dtype DT) into d_out.
template <int DT>
__global__ __launch_bounds__(128) void offset_net(
    const ushort* __restrict__ qT, const void* __restrict__ dww,
    const void* __restrict__ dwb, const void* __restrict__ lng,
    const void* __restrict__ lnb, const void* __restrict__ pww,
    float* __restrict__ pos, void* __restrict__ out,
    const int* __restrict__ flag, int b0) {
    if (flag[0] != DT) return;
    int n = blockIdx.y, sp = blockIdx.x, bl = n >> 2, bg = b0 + bl, g = n & 3;
    int i = sp >> 4, j = sp & 15, c = threadIdx.x;
    float acc = ldv<DT>(dwb, c);
#pragma unroll
    for (int dy = 0; dy < 3; dy++) {
        int yy = 2 * i - 1 + dy;
        if (yy < 0 || yy > 31) continue;
#pragma unroll
        for (int dx = 0; dx < 3; dx++) {
            int xx = 2 * j - 1 + dx;
            if (xx < 0 || xx > 31) continue;
            acc += ldv<DT>(dww, c * 9 + dy * 3 + dx) *
                   bf2f(qT[((size_t)bl * 1024 + yy * 32 + xx) * 512 + g * 128 + c]);
        }
    }
    __shared__ float rs[128], rs2[128];
    rs[c] = acc; rs2[c] = acc * acc;
    __syncthreads();
    for (int s2 = 64; s2 > 0; s2 >>= 1) {
        if (c < s2) { rs[c] += rs[c + s2]; rs2[c] += rs2[c + s2]; }
        __syncthreads();
    }
    float mu = rs[0] * (1.f / 128.f);
    float var = rs2[0] * (1.f / 128.f) - mu * mu;
    float xn = (acc - mu) * rsqrtf(fmaxf(var, 0.f) + 1e-5f);
    float gl = xn * ldv<DT>(lng, c) + ldv<DT>(lnb, c);
    gl = 0.5f * gl * (1.f + erff(gl * 0.70710678118654752f));  // exact GELU
    __syncthreads();
    rs[c] = gl * ldv<DT>(pww, c);
    rs2[c] = gl * ldv<DT>(pww, 128 + c);
    __syncthreads();
    for (int s2 = 64; s2 > 0; s2 >>= 1) {
        if (c < s2) { rs[c] += rs[c + s2]; rs2[c] += rs2[c + s2]; }
        __syncthreads();
    }
    if (c == 0) {
        float offy = tanhf(rs[0]) * (2.f / 15.f);
        float offx = tanhf(rs2[0]) * (2.f / 15.f);
        float ry = ((float)i + 0.5f) * (2.f / 15.f) - 1.f;
        float rx = ((float)j + 0.5f) * (2.f / 15.f) - 1.f;
        float py = sat(offy + ry, 1.2f), px = sat(offx + rx, 1.2f);
        size_t ol = ((size_t)(bl * 4 + g) * 256 + sp) * 2;   // chunk-local
        pos[ol] = py; pos[ol + 1] = px;
        size_t og = ((size_t)(bg * 4 + g) * 256 + sp) * 2;   // global out offset
        stv<DT>(out, 8388608 + og, py);
        stv<DT>(out, 8388608 + og + 1, px);
        stv<DT>(out, 8421376 + og, ry);
        stv<DT>(out, 8421376 + og + 1, rx);
    }
}

// ---------------------------------------------------------------------------
// Bilinear sample of x at pos -> xsT[bl][s][512] (internal bf16).
template <int DT>
__global__ __launch_bounds__(128) void sample_x(const void* __restrict__ x,
                                                const float* __restrict__ pos,
                                                ushort* __restrict__ xsT,
                                                const int* __restrict__ flag, int b0) {
    if (flag[0] != DT) return;
    int nl = blockIdx.y, s = blockIdx.x, bl = nl >> 2, bg = b0 + bl, g = nl & 3, c = threadIdx.x;
    size_t po = ((size_t)(bl * 4 + g) * 256 + s) * 2;
    float py = pos[po], px = pos[po + 1];
    float gx = (px + 1.f) * 15.5f;
    float gy = (py + 1.f) * 15.5f;
    float x0f = floorf(gx), y0f = floorf(gy);
    int ix0 = (int)x0f, iy0 = (int)y0f;
    float wx1 = gx - x0f, wx0 = 1.f - wx1, wy1 = gy - y0f, wy0 = 1.f - wy1;
    size_t xb = ((size_t)bg * 512 + g * 128 + c) * 1024;
    float acc = 0.f;
#define CORNER(ix, iy, wgt)                                            \
    if ((unsigned)(ix) < 32u && (unsigned)(iy) < 32u)                  \
        acc += (wgt) * ldv<DT>(x, xb + (iy) * 32 + (ix));
    CORNER(ix0, iy0, wx0 * wy0)
    CORNER(ix0 + 1, iy0, wx1 * wy0)
    CORNER(ix0, iy0 + 1, wx0 * wy1)
    CORNER(ix0 + 1, iy0 + 1, wx1 * wy1)
#undef CORNER
    xsT[((size_t)bl * 256 + s) * 512 + g * 128 + c] = f2bf(sat(acc, 64.f));
}

// ---------------------------------------------------------------------------
// Fused attention: logits = 0.125*QK^T + rpe_bias -> softmax -> PV -> outT.
template <int DT>
__global__ __launch_bounds__(256) void fused_attn(const ushort* __restrict__ qT,
                                                  const ushort* __restrict__ kT,
                                                  const ushort* __restrict__ vS,
                                                  const void* __restrict__ rpe,
                                                  const float* __restrict__ pos,
                                                  ushort* __restrict__ outT,
                                                  const int* __restrict__ flag) {
    if (flag[0] != DT) return;
    __shared__ __align__(16) ushort As[64][72];
    __shared__ __align__(16) ushort Pl[64][264];
    __shared__ ushort Tb[3969];
    __shared__ float Psf[512];
    __shared__ float red[64][4];
    __shared__ float rinv[64];
    int bh = blockIdx.y, bl = bh >> 3, h = bh & 7, g = h >> 1;
    int m0 = blockIdx.x * 64;
    int t = threadIdx.x;
    for (int i = t; i < 512; i += 256) {
        int r = i >> 3, c8 = (i & 7) * 8;
        *(uint4*)&As[r][c8] = *(const uint4*)&qT[((size_t)bl * 1024 + m0 + r) * 512 + h * 64 + c8];
    }
    for (int i = t; i < 3969; i += 256)
        Tb[i] = DT ? f2bf(((const float*)rpe)[(size_t)h * 3969 + i])
                   : ((const ushort*)rpe)[(size_t)h * 3969 + i];
    for (int i = t; i < 512; i += 256) Psf[i] = pos[(size_t)(bl * 4 + g) * 512 + i];
    __syncthreads();
    int w = t >> 6, lane = t & 63, col = lane & 15, quad = lane >> 4;
    int mw = w * 16;
    short8 a0 = *(const short8*)&As[mw + col][quad * 8];
    short8 a1 = *(const short8*)&As[mw + col][32 + quad * 8];
    const ushort* kbase = kT + (size_t)bl * 256 * 512 + h * 64;
    f32x4 acc[16] = {};
#pragma unroll
    for (int ni = 0; ni < 16; ni++) {
        short8 b0v = *(const short8*)&kbase[(size_t)(ni * 16 + col) * 512 + quad * 8];
        short8 b1v = *(const short8*)&kbase[(size_t)(ni * 16 + col) * 512 + 32 + quad * 8];
        acc[ni] = mfma_bf16(a0, b0v, acc[ni]);
        acc[ni] = mfma_bf16(a1, b1v, acc[ni]);
    }
#pragma unroll
    for (int ni = 0; ni < 16; ni++) {
        int s = ni * 16 + col;
        float psy = Psf[s * 2], psx = Psf[s * 2 + 1];
#pragma unroll
        for (int r = 0; r < 4; r++) {
            int m = m0 + mw + quad * 4 + r;
            float qy = (float)(m >> 5) * (2.f / 31.f) - 1.f;
            float qx = (float)(m & 31) * (2.f / 31.f) - 1.f;
            float gx = ((qx - psx) * 0.5f + 1.f) * 31.f;
            float gy = ((qy - psy) * 0.5f + 1.f) * 31.f;
            float x0f = floorf(gx), y0f = floorf(gy);
            int ix0 = (int)x0f, iy0 = (int)y0f;
            float wx1 = gx - x0f, wx0 = 1.f - wx1;
            float wy1 = gy - y0f, wy0 = 1.f - wy1;
            float bias = 0.f;
            if ((unsigned)ix0 < 63u && (unsigned)iy0 < 63u)
                bias += wx0 * wy0 * bf2f(Tb[iy0 * 63 + ix0]);
            if ((unsigned)(ix0 + 1) < 63u && (unsigned)iy0 < 63u)
                bias += wx1 * wy0 * bf2f(Tb[iy0 * 63 + ix0 + 1]);
            if ((unsigned)ix0 < 63u && (unsigned)(iy0 + 1) < 63u)
                bias += wx0 * wy1 * bf2f(Tb[(iy0 + 1) * 63 + ix0]);
            if ((unsigned)(ix0 + 1) < 63u && (unsigned)(iy0 + 1) < 63u)
                bias += wx1 * wy1 * bf2f(Tb[(iy0 + 1) * 63 + ix0 + 1]);
            Pl[mw + quad * 4 + r][s] = f2bf(sat(acc[ni][r] * 0.125f + bias, 64.f));
        }
    }
    __syncthreads();
    int r2 = t >> 2, qq = t & 3;
    uint4 ch[8];
#pragma unroll
    for (int i2 = 0; i2 < 8; i2++) ch[i2] = *(const uint4*)&Pl[r2][qq * 64 + i2 * 8];
    float mx = -3.0e38f;
#pragma unroll
    for (int i2 = 0; i2 < 8; i2++) {
        uint us[4] = {ch[i2].x, ch[i2].y, ch[i2].z, ch[i2].w};
#pragma unroll
        for (int k2 = 0; k2 < 4; k2++)
            mx = fmaxf(mx, fmaxf(bf2f(us[k2] & 0xffff), bf2f(us[k2] >> 16)));
    }
    red[r2][qq] = mx;
    __syncthreads();
    mx = fmaxf(fmaxf(red[r2][0], red[r2][1]), fmaxf(red[r2][2], red[r2][3]));
    __syncthreads();
    float sum = 0.f;
#pragma unroll
    for (int i2 = 0; i2 < 8; i2++) {
        uint us[4] = {ch[i2].x, ch[i2].y, ch[i2].z, ch[i2].w};
#pragma unroll
        for (int k2 = 0; k2 < 4; k2++) {
            float f0 = __expf(bf2f(us[k2] & 0xffff) - mx);
            float f1 = __expf(bf2f(us[k2] >> 16) - mx);
            sum += f0 + f1;
            uint pk = ((uint)f2bf(f1) << 16) | (uint)f2bf(f0);
            *(uint*)&Pl[r2][qq * 64 + i2 * 8 + k2 * 2] = pk;
        }
    }
    red[r2][qq] = sum;
    __syncthreads();
    if (qq == 0) rinv[r2] = 1.f / (red[r2][0] + red[r2][1] + red[r2][2] + red[r2][3]);
    __syncthreads();
    f32x4 acc2[4] = {};
    const ushort* vp = vS + ((size_t)bl * 512 + h * 64) * 256;
#pragma unroll
    for (int ks = 0; ks < 8; ks++) {
        short8 a = *(const short8*)&Pl[mw + col][ks * 32 + quad * 8];
#pragma unroll
        for (int ni = 0; ni < 4; ni++) {
            short8 bb = *(const short8*)&vp[(size_t)(ni * 16 + col) * 256 + ks * 32 + quad * 8];
            acc2[ni] = mfma_bf16(a, bb, acc2[ni]);
        }
    }
#pragma unroll
    for (int ni = 0; ni < 4; ni++)
#pragma unroll
        for (int r = 0; r < 4; r++) {
            int ml = mw + quad * 4 + r;
            float val = sat(acc2[ni][r] * rinv[ml], 64.f);
            outT[((size_t)bl * 1024 + m0 + ml) * 512 + h * 64 + ni * 16 + col] = f2bf(val);
        }
}

// ---------------------------------------------------------------------------
extern "C" void kernel_launch(void* const* d_in, const int* in_sizes, int n_in,
                              void* d_out, int out_size, void* d_ws, size_t ws_size,
                              hipStream_t stream) {
    const void* x   = d_in[0];
    const void* Wq  = d_in[1];
    const void* bq  = d_in[2];
    const void* Wk  = d_in[3];
    const void* bk  = d_in[4];
    const void* Wv  = d_in[5];
    const void* bv  = d_in[6];
    const void* Wo  = d_in[7];
    const void* bo  = d_in[8];
    const void* dww = d_in[9];
    const void* dwb = d_in[10];
    const void* lng = d_in[11];
    const void* lnb = d_in[12];
    const void* pww = d_in[13];
    const void* rpe = d_in[14];

    char* wsb = (char*)d_ws;
    int* flag = (int*)wsb;
    size_t base = 256;
    const size_t qT_b  = (size_t)1024 * 512 * 2;   // 1 MB
    const size_t xsT_b = (size_t)256 * 512 * 2;    // 256 KB
    const size_t kT_b  = (size_t)256 * 512 * 2;    // 256 KB
    const size_t vS_b  = (size_t)512 * 256 * 2;    // 256 KB
    const size_t oT_b  = (size_t)1024 * 512 * 2;   // 1 MB
    const size_t pos_b = (size_t)4 * 256 * 2 * 4;  // 8 KB
    const size_t per_b = qT_b + xsT_b + kT_b + vS_b + oT_b + pos_b + 1024;
    long long avail = (long long)ws_size - (long long)base;
    int bc_cap = (int)(avail > 0 ? avail / (long long)per_b : 0);
    if (bc_cap < 1) bc_cap = 1;
    if (bc_cap > 16) bc_cap = 16;

    dtype_probe<<<1, 64, 0, stream>>>(Wq, flag);

    for (int b0 = 0; b0 < 16; b0 += bc_cap) {
        int bc = 16 - b0 < bc_cap ? 16 - b0 : bc_cap;
        char* p = wsb + base;
        ushort* qT   = (ushort*)p; p += qT_b * bc;
        ushort* xsT  = (ushort*)p; p += xsT_b * bc;
        ushort* kT   = (ushort*)p; p += kT_b * bc;
        ushort* vS   = (ushort*)p; p += vS_b * bc;
        ushort* outT = (ushort*)p; p += oT_b * bc;
        float*  pos  = (float*)p;

        gemm_qx<0><<<dim3(16, 8, bc), 256, 0, stream>>>(Wq, x, bq, qT, flag, b0);
        gemm_qx<1><<<dim3(16, 8, bc), 256, 0, stream>>>(Wq, x, bq, qT, flag, b0);

        offset_net<0><<<dim3(256, 4 * bc), 128, 0, stream>>>(qT, dww, dwb, lng, lnb, pww,
                                                             pos, d_out, flag, b0);
        offset_net<1><<<dim3(256, 4 * bc), 128, 0, stream>>>(qT, dww, dwb, lng, lnb, pww,
                                                             pos, d_out, flag, b0);

        sample_x<0><<<dim3(256, 4 * bc), 128, 0, stream>>>(x, pos, xsT, flag, b0);
        sample_x<1><<<dim3(256, 4 * bc), 128, 0, stream>>>(x, pos, xsT, flag, b0);

        gemm_tn<1, 0, 1><<<dim3(4, 8, bc), 256, 0, stream>>>(Wk, xsT, bk, kT, flag, 512,
                                                             (size_t)256 * 512, (size_t)256 * 512, 512, 0);
        gemm_tn<1, 1, 1><<<dim3(4, 8, bc), 256, 0, stream>>>(Wk, xsT, bk, kT, flag, 512,
                                                             (size_t)256 * 512, (size_t)256 * 512, 512, 0);

        gemm_tn<0, 0, 1><<<dim3(4, 8, bc), 256, 0, stream>>>(Wv, xsT, bv, vS, flag, 512,
                                                             (size_t)256 * 512, (size_t)512 * 256, 256, 0);
        gemm_tn<0, 1, 1><<<dim3(4, 8, bc), 256, 0, stream>>>(Wv, xsT, bv, vS, flag, 512,
                                                             (size_t)256 * 512, (size_t)512 * 256, 256, 0);

        fused_attn<0><<<dim3(16, 8 * bc), 256, 0, stream>>>(qT, kT, vS, rpe, pos, outT, flag);
        fused_attn<1><<<dim3(16, 8 * bc), 256, 0, stream>>>(qT, kT, vS, rpe, pos, outT, flag);

        gemm_tn<0, 0, 0><<<dim3(16, 8, bc), 256, 0, stream>>>(Wo, outT, bo, d_out, flag, 512,
                                                              (size_t)1024 * 512, (size_t)512 * 1024, 1024,
                                                              (size_t)b0 * 512 * 1024);
        gemm_tn<0, 1, 0><<<dim3(16, 8, bc), 256, 0, stream>>>(Wo, outT, bo, d_out, flag, 512,
                                                              (size_t)1024 * 512, (size_t)512 * 1024, 1024,
                                                              (size_t)b0 * 512 * 1024);
    }
}

// Round 6
// 350.165 us; speedup vs baseline: 1.1779x; 1.1779x over previous
//
#include <hip/hip_runtime.h>

// Problem constants: B=16, NH=8, DH=64, NG=4, NC=512, CG=128, GH=2, H=W=32,
// HW=1024, Hs=Ws=16, NS=256, scale=0.125, ORF*off_range = 2/15.
// All external buffers are fp32 (established round 5); internals are bf16.

typedef __attribute__((ext_vector_type(8))) short short8;
typedef __attribute__((ext_vector_type(4))) float f32x4;

__device__ __forceinline__ float bf2f(ushort u) {
    union { uint i; float f; } c; c.i = ((uint)u) << 16; return c.f;
}
__device__ __forceinline__ ushort f2bf(float f) {
    union { float f; uint i; } c; c.f = f;
    uint x = c.i;
    return (ushort)((x + 0x7fffu + ((x >> 16) & 1u)) >> 16);  // RNE
}
__device__ __forceinline__ float sat(float v, float lim) {
    return fminf(fmaxf(v, -lim), lim);  // NaN-flushing clamp
}
// 8 consecutive fp32 -> bf16x8
__device__ __forceinline__ void ld8bf(ushort* dst, const float* p, size_t i) {
    float4 f0 = ((const float4*)p)[i / 4];
    float4 f1 = ((const float4*)p)[i / 4 + 1];
    dst[0] = f2bf(f0.x); dst[1] = f2bf(f0.y); dst[2] = f2bf(f0.z); dst[3] = f2bf(f0.w);
    dst[4] = f2bf(f1.x); dst[5] = f2bf(f1.y); dst[6] = f2bf(f1.z); dst[7] = f2bf(f1.w);
}
__device__ __forceinline__ f32x4 mfma_bf16(short8 a, short8 b, f32x4 c) {
    return __builtin_amdgcn_mfma_f32_16x16x32_bf16(a, b, c, 0, 0, 0);
}

// ---------------------------------------------------------------------------
// q = Wq*x + bq -> qT[bl][hw][c] (chunk-local, internal bf16).
__global__ __launch_bounds__(256) void gemm_qx(const float* __restrict__ A,
                                               const float* __restrict__ X,
                                               const float* __restrict__ bias,
                                               ushort* __restrict__ C, int b0) {
    __shared__ __align__(16) ushort As[64][72];
    __shared__ __align__(16) ushort Bs[64][72];
    int bl = blockIdx.z, bg = b0 + bl, m0 = blockIdx.y * 64, n0 = blockIdx.x * 64;
    size_t xbase = (size_t)bg * 512 * 1024;
    ushort* Cp = C + (size_t)bl * 1024 * 512;
    int t = threadIdx.x, w = t >> 6, lane = t & 63, col = lane & 15, quad = lane >> 4;
    int m_off = (w & 1) * 32, n_off = (w >> 1) * 32;
    f32x4 acc[2][2] = {};
    for (int k0 = 0; k0 < 512; k0 += 64) {
        __syncthreads();
        for (int i = t; i < 512; i += 256) {
            int r = i >> 3, c8 = (i & 7) * 8;
            ld8bf(&As[r][c8], A, (size_t)(m0 + r) * 512 + k0 + c8);
            ushort tmp[8];
            ld8bf(tmp, X, xbase + (size_t)(k0 + r) * 1024 + n0 + c8);
#pragma unroll
            for (int j = 0; j < 8; j++) Bs[c8 + j][r] = tmp[j];
        }
        __syncthreads();
#pragma unroll
        for (int kk = 0; kk < 2; kk++) {
            short8 a0 = *(const short8*)&As[m_off + col][kk * 32 + quad * 8];
            short8 a1 = *(const short8*)&As[m_off + 16 + col][kk * 32 + quad * 8];
            short8 b0v = *(const short8*)&Bs[n_off + col][kk * 32 + quad * 8];
            short8 b1v = *(const short8*)&Bs[n_off + 16 + col][kk * 32 + quad * 8];
            acc[0][0] = mfma_bf16(a0, b0v, acc[0][0]);
            acc[0][1] = mfma_bf16(a0, b1v, acc[0][1]);
            acc[1][0] = mfma_bf16(a1, b0v, acc[1][0]);
            acc[1][1] = mfma_bf16(a1, b1v, acc[1][1]);
        }
    }
#pragma unroll
    for (int mi = 0; mi < 2; mi++)
#pragma unroll
        for (int ni = 0; ni < 2; ni++) {
            int mg = m0 + m_off + mi * 16 + quad * 4;
            int ng = n0 + n_off + ni * 16 + col;
            f32x4 vv = acc[mi][ni];
            ushort4 pk;
            pk.x = f2bf(sat(vv[0] + bias[mg + 0], 1e4f));
            pk.y = f2bf(sat(vv[1] + bias[mg + 1], 1e4f));
            pk.z = f2bf(sat(vv[2] + bias[mg + 2], 1e4f));
            pk.w = f2bf(sat(vv[3] + bias[mg + 3], 1e4f));
            *(ushort4*)&Cp[(size_t)ng * 512 + mg] = pk;
        }
}

// ---------------------------------------------------------------------------
// C[m][n] = sum_k A[m][k]*B[n][k] + bias[m]. A fp32, B internal bf16.
// OUT_T=1: packed C^T bf16. OUT_T=0: row-major; CINT=1 bf16, CINT=0 fp32.
template <int OUT_T, int CINT>
__global__ __launch_bounds__(256) void gemm_tn(const float* __restrict__ A,
                                               const ushort* __restrict__ Bm,
                                               const float* __restrict__ bias,
                                               void* __restrict__ C, int K,
                                               size_t sB, size_t sC, int ldc, size_t c0) {
    __shared__ __align__(16) ushort As[64][72];
    __shared__ __align__(16) ushort Bs[64][72];
    int b = blockIdx.z, m0 = blockIdx.y * 64, n0 = blockIdx.x * 64;
    const ushort* Bp = Bm + (size_t)b * sB;
    size_t cb = c0 + (size_t)b * sC;
    int t = threadIdx.x, w = t >> 6, lane = t & 63, col = lane & 15, quad = lane >> 4;
    int m_off = (w & 1) * 32, n_off = (w >> 1) * 32;
    f32x4 acc[2][2] = {};
    for (int k0 = 0; k0 < K; k0 += 64) {
        __syncthreads();
        for (int i = t; i < 512; i += 256) {
            int r = i >> 3, c8 = (i & 7) * 8;
            ld8bf(&As[r][c8], A, (size_t)(m0 + r) * K + k0 + c8);
            *(uint4*)&Bs[r][c8] = *(const uint4*)&Bp[(size_t)(n0 + r) * K + k0 + c8];
        }
        __syncthreads();
#pragma unroll
        for (int kk = 0; kk < 2; kk++) {
            short8 a0 = *(const short8*)&As[m_off + col][kk * 32 + quad * 8];
            short8 a1 = *(const short8*)&As[m_off + 16 + col][kk * 32 + quad * 8];
            short8 b0v = *(const short8*)&Bs[n_off + col][kk * 32 + quad * 8];
            short8 b1v = *(const short8*)&Bs[n_off + 16 + col][kk * 32 + quad * 8];
            acc[0][0] = mfma_bf16(a0, b0v, acc[0][0]);
            acc[0][1] = mfma_bf16(a0, b1v, acc[0][1]);
            acc[1][0] = mfma_bf16(a1, b0v, acc[1][0]);
            acc[1][1] = mfma_bf16(a1, b1v, acc[1][1]);
        }
    }
#pragma unroll
    for (int mi = 0; mi < 2; mi++)
#pragma unroll
        for (int ni = 0; ni < 2; ni++) {
            int mg = m0 + m_off + mi * 16 + quad * 4;
            int ng = n0 + n_off + ni * 16 + col;
            f32x4 vv = acc[mi][ni];
            if (OUT_T == 1) {
                ushort4 pk;
                pk.x = f2bf(sat(vv[0] + bias[mg + 0], 1e4f));
                pk.y = f2bf(sat(vv[1] + bias[mg + 1], 1e4f));
                pk.z = f2bf(sat(vv[2] + bias[mg + 2], 1e4f));
                pk.w = f2bf(sat(vv[3] + bias[mg + 3], 1e4f));
                *(ushort4*)&((ushort*)C)[cb + (size_t)ng * ldc + mg] = pk;
            } else {
#pragma unroll
                for (int r = 0; r < 4; r++) {
                    float v = sat(vv[r] + bias[mg + r], 1e4f);
                    if (CINT) ((ushort*)C)[cb + (size_t)(mg + r) * ldc + ng] = f2bf(v);
                    else ((float*)C)[cb + (size_t)(mg + r) * ldc + ng] = v;
                }
            }
        }
}

// ---------------------------------------------------------------------------
// Offset network: depthwise 3x3 s2 p1 -> LN(channel) -> GELU -> 1x1 -> tanh*2/15.
__global__ __launch_bounds__(128) void offset_net(
    const ushort* __restrict__ qT, const float* __restrict__ dww,
    const float* __restrict__ dwb, const float* __restrict__ lng,
    const float* __restrict__ lnb, const float* __restrict__ pww,
    float* __restrict__ pos, float* __restrict__ out, int b0) {
    int n = blockIdx.y, sp = blockIdx.x, bl = n >> 2, bg = b0 + bl, g = n & 3;
    int i = sp >> 4, j = sp & 15, c = threadIdx.x;
    float acc = dwb[c];
#pragma unroll
    for (int dy = 0; dy < 3; dy++) {
        int yy = 2 * i - 1 + dy;
        if (yy < 0 || yy > 31) continue;
#pragma unroll
        for (int dx = 0; dx < 3; dx++) {
            int xx = 2 * j - 1 + dx;
            if (xx < 0 || xx > 31) continue;
            acc += dww[c * 9 + dy * 3 + dx] *
                   bf2f(qT[((size_t)bl * 1024 + yy * 32 + xx) * 512 + g * 128 + c]);
        }
    }
    __shared__ float rs[128], rs2[128];
    rs[c] = acc; rs2[c] = acc * acc;
    __syncthreads();
    for (int s2 = 64; s2 > 0; s2 >>= 1) {
        if (c < s2) { rs[c] += rs[c + s2]; rs2[c] += rs2[c + s2]; }
        __syncthreads();
    }
    float mu = rs[0] * (1.f / 128.f);
    float var = rs2[0] * (1.f / 128.f) - mu * mu;
    float xn = (acc - mu) * rsqrtf(fmaxf(var, 0.f) + 1e-5f);
    float gl = xn * lng[c] + lnb[c];
    gl = 0.5f * gl * (1.f + erff(gl * 0.70710678118654752f));  // exact GELU
    __syncthreads();
    rs[c] = gl * pww[c];
    rs2[c] = gl * pww[128 + c];
    __syncthreads();
    for (int s2 = 64; s2 > 0; s2 >>= 1) {
        if (c < s2) { rs[c] += rs[c + s2]; rs2[c] += rs2[c + s2]; }
        __syncthreads();
    }
    if (c == 0) {
        float offy = tanhf(rs[0]) * (2.f / 15.f);
        float offx = tanhf(rs2[0]) * (2.f / 15.f);
        float ry = ((float)i + 0.5f) * (2.f / 15.f) - 1.f;
        float rx = ((float)j + 0.5f) * (2.f / 15.f) - 1.f;
        float py = sat(offy + ry, 1.2f), px = sat(offx + rx, 1.2f);
        size_t ol = ((size_t)(bl * 4 + g) * 256 + sp) * 2;   // chunk-local
        pos[ol] = py; pos[ol + 1] = px;
        size_t og = ((size_t)(bg * 4 + g) * 256 + sp) * 2;   // global out offset
        out[8388608 + og] = py;  out[8388608 + og + 1] = px;
        out[8421376 + og] = ry;  out[8421376 + og + 1] = rx;
    }
}

// ---------------------------------------------------------------------------
// Bilinear sample of x at pos -> xsT[bl][s][512] (internal bf16).
__global__ __launch_bounds__(128) void sample_x(const float* __restrict__ x,
                                                const float* __restrict__ pos,
                                                ushort* __restrict__ xsT, int b0) {
    int nl = blockIdx.y, s = blockIdx.x, bl = nl >> 2, bg = b0 + bl, g = nl & 3, c = threadIdx.x;
    size_t po = ((size_t)(bl * 4 + g) * 256 + s) * 2;
    float py = pos[po], px = pos[po + 1];
    float gx = (px + 1.f) * 15.5f;
    float gy = (py + 1.f) * 15.5f;
    float x0f = floorf(gx), y0f = floorf(gy);
    int ix0 = (int)x0f, iy0 = (int)y0f;
    float wx1 = gx - x0f, wx0 = 1.f - wx1, wy1 = gy - y0f, wy0 = 1.f - wy1;
    size_t xb = ((size_t)bg * 512 + g * 128 + c) * 1024;
    float acc = 0.f;
#define CORNER(ix, iy, wgt)                                            \
    if ((unsigned)(ix) < 32u && (unsigned)(iy) < 32u)                  \
        acc += (wgt) * x[xb + (iy) * 32 + (ix)];
    CORNER(ix0, iy0, wx0 * wy0)
    CORNER(ix0 + 1, iy0, wx1 * wy0)
    CORNER(ix0, iy0 + 1, wx0 * wy1)
    CORNER(ix0 + 1, iy0 + 1, wx1 * wy1)
#undef CORNER
    xsT[((size_t)bl * 256 + s) * 512 + g * 128 + c] = f2bf(sat(acc, 64.f));
}

// ---------------------------------------------------------------------------
// Fused attention v2: per-s precomputed bilinear weights, zero-padded 64x64
// table, x-corner sharing, in-register softmax, single LDS P round-trip.
__global__ __launch_bounds__(256) void fused_attn(const ushort* __restrict__ qT,
                                                  const ushort* __restrict__ kT,
                                                  const ushort* __restrict__ vS,
                                                  const float* __restrict__ rpe,
                                                  const float* __restrict__ pos,
                                                  ushort* __restrict__ outT) {
    __shared__ __align__(16) ushort Pl[64][264];   // 264*2=528B row (16B mult)
    __shared__ ushort Tb[4096];                    // 64x64, row/col 63 = zeros
    __shared__ int   sIX[256], sIY[256];
    __shared__ float4 sW4[256];
    int bh = blockIdx.y, bl = bh >> 3, h = bh & 7, g = h >> 1;
    int m0 = blockIdx.x * 64;
    int t = threadIdx.x;
    for (int i = t; i < 4096; i += 256) {
        int yy = i >> 6, xx = i & 63;
        float v = (yy < 63 && xx < 63) ? rpe[(size_t)h * 3969 + yy * 63 + xx] : 0.f;
        Tb[i] = f2bf(v);
    }
    {
        int s = t;
        float psy = pos[(size_t)(bl * 4 + g) * 512 + 2 * s];
        float psx = pos[(size_t)(bl * 4 + g) * 512 + 2 * s + 1];
        float syf = 15.5f - 15.5f * psy;
        float sxf = 15.5f - 15.5f * psx;
        float fy = floorf(syf), fx = floorf(sxf);
        float wy1 = syf - fy, wy0 = 1.f - wy1;
        float wx1 = sxf - fx, wx0 = 1.f - wx1;
        sIY[s] = (int)fy; sIX[s] = (int)fx;
        sW4[s] = make_float4(wx0 * wy0, wx1 * wy0, wx0 * wy1, wx1 * wy1);
    }
    __syncthreads();
    int w = t >> 6, lane = t & 63, col = lane & 15, quad = lane >> 4;
    int mw = w * 16;
    // q A-fragments direct from global
    const ushort* qrow = qT + ((size_t)bl * 1024 + m0 + mw + col) * 512 + h * 64;
    short8 a0 = *(const short8*)&qrow[quad * 8];
    short8 a1 = *(const short8*)&qrow[32 + quad * 8];
    const ushort* kbase = kT + (size_t)bl * 256 * 512 + h * 64;
    f32x4 acc[16] = {};
#pragma unroll
    for (int ni = 0; ni < 16; ni++) {
        short8 b0v = *(const short8*)&kbase[(size_t)(ni * 16 + col) * 512 + quad * 8];
        short8 b1v = *(const short8*)&kbase[(size_t)(ni * 16 + col) * 512 + 32 + quad * 8];
        acc[ni] = mfma_bf16(a0, b0v, acc[ni]);
        acc[ni] = mfma_bf16(a1, b1v, acc[ni]);
    }
    // epilogue: logits = acc*scale + bias (bias via shared x-corner loads)
    int mbase = m0 + mw;            // multiple of 16
    int my = mbase >> 5;            // wave-constant row block
    int mxq = (mbase & 31) + quad * 4;
#pragma unroll
    for (int ni = 0; ni < 16; ni++) {
        int s = ni * 16 + col;
        int p = mxq + sIX[s];
        int iy0 = my + sIY[s];
        float4 w4 = sW4[s];
        int ry0 = ((unsigned)iy0 < 63u) ? (iy0 << 6) : (63 << 6);
        int ry1 = ((unsigned)(iy0 + 1) < 63u) ? ((iy0 + 1) << 6) : (63 << 6);
        float t0[5], t1[5];
#pragma unroll
        for (int j = 0; j < 5; j++) {
            int pj = p + j;
            int cx = ((unsigned)pj < 63u) ? pj : 63;
            t0[j] = bf2f(Tb[ry0 + cx]);
            t1[j] = bf2f(Tb[ry1 + cx]);
        }
#pragma unroll
        for (int r = 0; r < 4; r++) {
            float bias = w4.x * t0[r] + w4.y * t0[r + 1] + w4.z * t1[r] + w4.w * t1[r + 1];
            acc[ni][r] = sat(acc[ni][r] * 0.125f + bias, 64.f);
        }
    }
    // in-register softmax: rows quad*4+r live in 16-lane groups (same quad)
    float rinv_[4];
#pragma unroll
    for (int r = 0; r < 4; r++) {
        float mr = acc[0][r];
#pragma unroll
        for (int ni = 1; ni < 16; ni++) mr = fmaxf(mr, acc[ni][r]);
#pragma unroll
        for (int off = 1; off < 16; off <<= 1) mr = fmaxf(mr, __shfl_xor(mr, off));
        float sr = 0.f;
#pragma unroll
        for (int ni = 0; ni < 16; ni++) {
            float e = __expf(acc[ni][r] - mr);
            acc[ni][r] = e;
            sr += e;
        }
#pragma unroll
        for (int off = 1; off < 16; off <<= 1) sr += __shfl_xor(sr, off);
        rinv_[r] = 1.f / sr;
    }
    // P (bf16) -> LDS in A-fragment layout source (row-major rows of the strip)
#pragma unroll
    for (int ni = 0; ni < 16; ni++)
#pragma unroll
        for (int r = 0; r < 4; r++)
            Pl[mw + quad * 4 + r][ni * 16 + col] = f2bf(acc[ni][r]);
    __syncthreads();
    // PV
    f32x4 acc2[4] = {};
    const ushort* vp = vS + ((size_t)bl * 512 + h * 64) * 256;
#pragma unroll
    for (int ks = 0; ks < 8; ks++) {
        short8 a = *(const short8*)&Pl[mw + col][ks * 32 + quad * 8];
#pragma unroll
        for (int ni = 0; ni < 4; ni++) {
            short8 bb = *(const short8*)&vp[(size_t)(ni * 16 + col) * 256 + ks * 32 + quad * 8];
            acc2[ni] = mfma_bf16(a, bb, acc2[ni]);
        }
    }
#pragma unroll
    for (int ni = 0; ni < 4; ni++)
#pragma unroll
        for (int r = 0; r < 4; r++) {
            int ml = mw + quad * 4 + r;
            float val = sat(acc2[ni][r] * rinv_[r], 64.f);
            outT[((size_t)bl * 1024 + m0 + ml) * 512 + h * 64 + ni * 16 + col] = f2bf(val);
        }
}

// ---------------------------------------------------------------------------
extern "C" void kernel_launch(void* const* d_in, const int* in_sizes, int n_in,
                              void* d_out, int out_size, void* d_ws, size_t ws_size,
                              hipStream_t stream) {
    const float* x   = (const float*)d_in[0];
    const float* Wq  = (const float*)d_in[1];
    const float* bq  = (const float*)d_in[2];
    const float* Wk  = (const float*)d_in[3];
    const float* bk  = (const float*)d_in[4];
    const float* Wv  = (const float*)d_in[5];
    const float* bv  = (const float*)d_in[6];
    const float* Wo  = (const float*)d_in[7];
    const float* bo  = (const float*)d_in[8];
    const float* dww = (const float*)d_in[9];
    const float* dwb = (const float*)d_in[10];
    const float* lng = (const float*)d_in[11];
    const float* lnb = (const float*)d_in[12];
    const float* pww = (const float*)d_in[13];
    const float* rpe = (const float*)d_in[14];
    float* out = (float*)d_out;

    char* wsb = (char*)d_ws;
    size_t base = 256;
    const size_t qT_b  = (size_t)1024 * 512 * 2;   // 1 MB
    const size_t xsT_b = (size_t)256 * 512 * 2;    // 256 KB
    const size_t kT_b  = (size_t)256 * 512 * 2;    // 256 KB
    const size_t vS_b  = (size_t)512 * 256 * 2;    // 256 KB
    const size_t oT_b  = (size_t)1024 * 512 * 2;   // 1 MB
    const size_t pos_b = (size_t)4 * 256 * 2 * 4;  // 8 KB
    const size_t per_b = qT_b + xsT_b + kT_b + vS_b + oT_b + pos_b + 1024;
    long long avail = (long long)ws_size - (long long)base;
    int bc_cap = (int)(avail > 0 ? avail / (long long)per_b : 0);
    if (bc_cap < 1) bc_cap = 1;
    if (bc_cap > 16) bc_cap = 16;

    for (int b0 = 0; b0 < 16; b0 += bc_cap) {
        int bc = 16 - b0 < bc_cap ? 16 - b0 : bc_cap;
        char* p = wsb + base;
        ushort* qT   = (ushort*)p; p += qT_b * bc;
        ushort* xsT  = (ushort*)p; p += xsT_b * bc;
        ushort* kT   = (ushort*)p; p += kT_b * bc;
        ushort* vS   = (ushort*)p; p += vS_b * bc;
        ushort* outT = (ushort*)p; p += oT_b * bc;
        float*  pos  = (float*)p;

        gemm_qx<<<dim3(16, 8, bc), 256, 0, stream>>>(Wq, x, bq, qT, b0);
        offset_net<<<dim3(256, 4 * bc), 128, 0, stream>>>(qT, dww, dwb, lng, lnb, pww,
                                                          pos, out, b0);
        sample_x<<<dim3(256, 4 * bc), 128, 0, stream>>>(x, pos, xsT, b0);
        gemm_tn<1, 1><<<dim3(4, 8, bc), 256, 0, stream>>>(Wk, xsT, bk, kT, 512,
                                                          (size_t)256 * 512, (size_t)256 * 512, 512, 0);
        gemm_tn<0, 1><<<dim3(4, 8, bc), 256, 0, stream>>>(Wv, xsT, bv, vS, 512,
                                                          (size_t)256 * 512, (size_t)512 * 256, 256, 0);
        fused_attn<<<dim3(16, 8 * bc), 256, 0, stream>>>(qT, kT, vS, rpe, pos, outT);
        gemm_tn<0, 0><<<dim3(16, 8, bc), 256, 0, stream>>>(Wo, outT, bo, d_out, 512,
                                                           (size_t)1024 * 512, (size_t)512 * 1024, 1024,
                                                           (size_t)b0 * 512 * 1024);
    }
}

// Round 7
// 314.847 us; speedup vs baseline: 1.3100x; 1.1122x over previous
//
#include <hip/hip_runtime.h>

// Problem constants: B=16, NH=8, DH=64, NG=4, NC=512, CG=128, GH=2, H=W=32,
// HW=1024, Hs=Ws=16, NS=256, scale=0.125, ORF*off_range = 2/15.
// External buffers fp32; internal tensors bf16.

typedef __attribute__((ext_vector_type(8))) short short8;
typedef __attribute__((ext_vector_type(4))) float f32x4;

__device__ __forceinline__ float bf2f(ushort u) {
    union { uint i; float f; } c; c.i = ((uint)u) << 16; return c.f;
}
__device__ __forceinline__ ushort f2bf(float f) {
    union { float f; uint i; } c; c.f = f;
    uint x = c.i;
    return (ushort)((x + 0x7fffu + ((x >> 16) & 1u)) >> 16);  // RNE
}
__device__ __forceinline__ float sat(float v, float lim) {
    return fminf(fmaxf(v, -lim), lim);  // NaN-flushing clamp
}
__device__ __forceinline__ f32x4 mfma_bf16(short8 a, short8 b, f32x4 c) {
    return __builtin_amdgcn_mfma_f32_16x16x32_bf16(a, b, c, 0, 0, 0);
}

// ---------------------------------------------------------------------------
// One-time preps
// Convert 4 weight matrices (512x512 fp32) to bf16.
__global__ __launch_bounds__(256) void prep_w(const float* __restrict__ w0,
                                              const float* __restrict__ w1,
                                              const float* __restrict__ w2,
                                              const float* __restrict__ w3,
                                              ushort* __restrict__ dst) {
    int widx = blockIdx.y;
    const float* src = widx == 0 ? w0 : widx == 1 ? w1 : widx == 2 ? w2 : w3;
    int i = blockIdx.x * 256 + threadIdx.x;
    float4 f = ((const float4*)src)[i];
    ushort4 u;
    u.x = f2bf(f.x); u.y = f2bf(f.y); u.z = f2bf(f.z); u.w = f2bf(f.w);
    ((ushort4*)(dst + (size_t)widx * 262144))[i] = u;
}

// rpe [8][63][63] fp32 -> padded bf16 [8][64][64] (row/col 63 zero)
__global__ __launch_bounds__(256) void prep_rpe(const float* __restrict__ rpe,
                                                ushort* __restrict__ tb8) {
    int h = blockIdx.x, t = threadIdx.x;
    for (int i = t; i < 4096; i += 256) {
        int yy = i >> 6, xx = i & 63;
        float v = (yy < 63 && xx < 63) ? rpe[(size_t)h * 3969 + yy * 63 + xx] : 0.f;
        tb8[(size_t)h * 4096 + i] = f2bf(v);
    }
}

// x [b][512][1024] fp32 -> xbT [bl][1024][512] bf16 (transpose+convert)
__global__ __launch_bounds__(256) void prep_xT(const float* __restrict__ x,
                                               ushort* __restrict__ xbT, int b0) {
    __shared__ float tile[64][33];
    int n0 = blockIdx.x * 32, c0 = blockIdx.y * 64, bl = blockIdx.z, bg = b0 + bl;
    int t = threadIdx.x;
#pragma unroll
    for (int it = 0; it < 8; it++) {
        int cr = it * 8 + (t >> 5), col = t & 31;
        tile[cr][col] = x[((size_t)bg * 512 + c0 + cr) * 1024 + n0 + col];
    }
    __syncthreads();
#pragma unroll
    for (int it = 0; it < 8; it++) {
        int nr = it * 4 + (t >> 6), cc = t & 63;
        xbT[((size_t)bl * 1024 + n0 + nr) * 512 + c0 + cc] = f2bf(tile[cc][nr]);
    }
}

// ---------------------------------------------------------------------------
// C[m][n] = sum_k A[m][k]*B[n][k] + bias[m]. A,B bf16. bias fp32.
// OUT_T=1: write C^T bf16 packed. OUT_T=0: row-major; CINT=1 bf16, CINT=0 fp32.
template <int OUT_T, int CINT>
__global__ __launch_bounds__(256) void gemm_tn(const ushort* __restrict__ A,
                                               const ushort* __restrict__ Bm,
                                               const float* __restrict__ bias,
                                               void* __restrict__ C, int K,
                                               size_t sB, size_t sC, int ldc, size_t c0) {
    __shared__ __align__(16) ushort As[64][72];
    __shared__ __align__(16) ushort Bs[64][72];
    int b = blockIdx.z, m0 = blockIdx.y * 64, n0 = blockIdx.x * 64;
    const ushort* Bp = Bm + (size_t)b * sB;
    size_t cb = c0 + (size_t)b * sC;
    int t = threadIdx.x, w = t >> 6, lane = t & 63, col = lane & 15, quad = lane >> 4;
    int m_off = (w & 1) * 32, n_off = (w >> 1) * 32;
    f32x4 acc[2][2] = {};
    for (int k0 = 0; k0 < K; k0 += 64) {
        __syncthreads();
        for (int i = t; i < 512; i += 256) {
            int r = i >> 3, c8 = (i & 7) * 8;
            *(uint4*)&As[r][c8] = *(const uint4*)&A[(size_t)(m0 + r) * K + k0 + c8];
            *(uint4*)&Bs[r][c8] = *(const uint4*)&Bp[(size_t)(n0 + r) * K + k0 + c8];
        }
        __syncthreads();
#pragma unroll
        for (int kk = 0; kk < 2; kk++) {
            short8 a0 = *(const short8*)&As[m_off + col][kk * 32 + quad * 8];
            short8 a1 = *(const short8*)&As[m_off + 16 + col][kk * 32 + quad * 8];
            short8 b0v = *(const short8*)&Bs[n_off + col][kk * 32 + quad * 8];
            short8 b1v = *(const short8*)&Bs[n_off + 16 + col][kk * 32 + quad * 8];
            acc[0][0] = mfma_bf16(a0, b0v, acc[0][0]);
            acc[0][1] = mfma_bf16(a0, b1v, acc[0][1]);
            acc[1][0] = mfma_bf16(a1, b0v, acc[1][0]);
            acc[1][1] = mfma_bf16(a1, b1v, acc[1][1]);
        }
    }
#pragma unroll
    for (int mi = 0; mi < 2; mi++)
#pragma unroll
        for (int ni = 0; ni < 2; ni++) {
            int mg = m0 + m_off + mi * 16 + quad * 4;
            int ng = n0 + n_off + ni * 16 + col;
            f32x4 vv = acc[mi][ni];
            if (OUT_T == 1) {
                ushort4 pk;
                pk.x = f2bf(sat(vv[0] + bias[mg + 0], 1e4f));
                pk.y = f2bf(sat(vv[1] + bias[mg + 1], 1e4f));
                pk.z = f2bf(sat(vv[2] + bias[mg + 2], 1e4f));
                pk.w = f2bf(sat(vv[3] + bias[mg + 3], 1e4f));
                *(ushort4*)&((ushort*)C)[cb + (size_t)ng * ldc + mg] = pk;
            } else {
#pragma unroll
                for (int r = 0; r < 4; r++) {
                    float v = sat(vv[r] + bias[mg + r], 1e4f);
                    if (CINT) ((ushort*)C)[cb + (size_t)(mg + r) * ldc + ng] = f2bf(v);
                    else ((float*)C)[cb + (size_t)(mg + r) * ldc + ng] = v;
                }
            }
        }
}

// ---------------------------------------------------------------------------
// Offset network: depthwise 3x3 s2 p1 -> LN(channel) -> GELU -> 1x1 -> tanh*2/15.
__global__ __launch_bounds__(128) void offset_net(
    const ushort* __restrict__ qT, const float* __restrict__ dww,
    const float* __restrict__ dwb, const float* __restrict__ lng,
    const float* __restrict__ lnb, const float* __restrict__ pww,
    float* __restrict__ pos, float* __restrict__ out, int b0) {
    int n = blockIdx.y, sp = blockIdx.x, bl = n >> 2, bg = b0 + bl, g = n & 3;
    int i = sp >> 4, j = sp & 15, c = threadIdx.x;
    float acc = dwb[c];
#pragma unroll
    for (int dy = 0; dy < 3; dy++) {
        int yy = 2 * i - 1 + dy;
        if (yy < 0 || yy > 31) continue;
#pragma unroll
        for (int dx = 0; dx < 3; dx++) {
            int xx = 2 * j - 1 + dx;
            if (xx < 0 || xx > 31) continue;
            acc += dww[c * 9 + dy * 3 + dx] *
                   bf2f(qT[((size_t)bl * 1024 + yy * 32 + xx) * 512 + g * 128 + c]);
        }
    }
    __shared__ float rs[128], rs2[128];
    rs[c] = acc; rs2[c] = acc * acc;
    __syncthreads();
    for (int s2 = 64; s2 > 0; s2 >>= 1) {
        if (c < s2) { rs[c] += rs[c + s2]; rs2[c] += rs2[c + s2]; }
        __syncthreads();
    }
    float mu = rs[0] * (1.f / 128.f);
    float var = rs2[0] * (1.f / 128.f) - mu * mu;
    float xn = (acc - mu) * rsqrtf(fmaxf(var, 0.f) + 1e-5f);
    float gl = xn * lng[c] + lnb[c];
    gl = 0.5f * gl * (1.f + erff(gl * 0.70710678118654752f));  // exact GELU
    __syncthreads();
    rs[c] = gl * pww[c];
    rs2[c] = gl * pww[128 + c];
    __syncthreads();
    for (int s2 = 64; s2 > 0; s2 >>= 1) {
        if (c < s2) { rs[c] += rs[c + s2]; rs2[c] += rs2[c + s2]; }
        __syncthreads();
    }
    if (c == 0) {
        float offy = tanhf(rs[0]) * (2.f / 15.f);
        float offx = tanhf(rs2[0]) * (2.f / 15.f);
        float ry = ((float)i + 0.5f) * (2.f / 15.f) - 1.f;
        float rx = ((float)j + 0.5f) * (2.f / 15.f) - 1.f;
        float py = sat(offy + ry, 1.2f), px = sat(offx + rx, 1.2f);
        size_t ol = ((size_t)(bl * 4 + g) * 256 + sp) * 2;   // chunk-local
        pos[ol] = py; pos[ol + 1] = px;
        size_t og = ((size_t)(bg * 4 + g) * 256 + sp) * 2;   // global out offset
        out[8388608 + og] = py;  out[8388608 + og + 1] = px;
        out[8421376 + og] = ry;  out[8421376 + og + 1] = rx;
    }
}

// ---------------------------------------------------------------------------
// Bilinear sample of x at pos -> xsT[bl][s][512] (bf16).
__global__ __launch_bounds__(128) void sample_x(const float* __restrict__ x,
                                                const float* __restrict__ pos,
                                                ushort* __restrict__ xsT, int b0) {
    int nl = blockIdx.y, s = blockIdx.x, bl = nl >> 2, bg = b0 + bl, g = nl & 3, c = threadIdx.x;
    size_t po = ((size_t)(bl * 4 + g) * 256 + s) * 2;
    float py = pos[po], px = pos[po + 1];
    float gx = (px + 1.f) * 15.5f;
    float gy = (py + 1.f) * 15.5f;
    float x0f = floorf(gx), y0f = floorf(gy);
    int ix0 = (int)x0f, iy0 = (int)y0f;
    float wx1 = gx - x0f, wx0 = 1.f - wx1, wy1 = gy - y0f, wy0 = 1.f - wy1;
    size_t xb = ((size_t)bg * 512 + g * 128 + c) * 1024;
    float acc = 0.f;
#define CORNER(ix, iy, wgt)                                            \
    if ((unsigned)(ix) < 32u && (unsigned)(iy) < 32u)                  \
        acc += (wgt) * x[xb + (iy) * 32 + (ix)];
    CORNER(ix0, iy0, wx0 * wy0)
    CORNER(ix0 + 1, iy0, wx1 * wy0)
    CORNER(ix0, iy0 + 1, wx0 * wy1)
    CORNER(ix0 + 1, iy0 + 1, wx1 * wy1)
#undef CORNER
    xsT[((size_t)bl * 256 + s) * 512 + g * 128 + c] = f2bf(sat(acc, 64.f));
}

// ---------------------------------------------------------------------------
// Fused attention v3: K staged in LDS (union with P), prepped bf16 rpe table,
// per-s bilinear weights, in-register softmax, relaxed VGPR cap.
__global__ __launch_bounds__(256, 2) void fused_attn(const ushort* __restrict__ qT,
                                                     const ushort* __restrict__ kT,
                                                     const ushort* __restrict__ vS,
                                                     const ushort* __restrict__ tb8,
                                                     const float* __restrict__ pos,
                                                     ushort* __restrict__ outT) {
    __shared__ __align__(16) ushort KP[256 * 72];  // K phase: Ks[s][72]; P phase: Pl[m*264+s]
    __shared__ __align__(16) ushort Tb[4096];
    __shared__ float4 sW4[256];
    __shared__ int sIX[256], sIY[256];
    int bh = blockIdx.y, bl = bh >> 3, h = bh & 7, g = h >> 1;
    int m0 = blockIdx.x * 64;
    int t = threadIdx.x;
    // stage K tile (256 s x 64 k bf16), coalesced
    {
        const ushort* kb = kT + (size_t)bl * 256 * 512 + h * 64;
        for (int i = t; i < 2048; i += 256) {
            int s = i >> 3, part = i & 7;
            *(uint4*)&KP[s * 72 + part * 8] = *(const uint4*)&kb[(size_t)s * 512 + part * 8];
        }
    }
    for (int i = t; i < 512; i += 256)
        ((uint4*)Tb)[i] = ((const uint4*)(tb8 + (size_t)h * 4096))[i];
    {
        int s = t;
        float psy = pos[(size_t)(bl * 4 + g) * 512 + 2 * s];
        float psx = pos[(size_t)(bl * 4 + g) * 512 + 2 * s + 1];
        float syf = 15.5f - 15.5f * psy;
        float sxf = 15.5f - 15.5f * psx;
        float fy = floorf(syf), fx = floorf(sxf);
        float wy1 = syf - fy, wy0 = 1.f - wy1;
        float wx1 = sxf - fx, wx0 = 1.f - wx1;
        sIY[s] = (int)fy; sIX[s] = (int)fx;
        sW4[s] = make_float4(wx0 * wy0, wx1 * wy0, wx0 * wy1, wx1 * wy1);
    }
    __syncthreads();
    int w = t >> 6, lane = t & 63, col = lane & 15, quad = lane >> 4;
    int mw = w * 16;
    // q A-fragments from global
    const ushort* qrow = qT + ((size_t)bl * 1024 + m0 + mw + col) * 512 + h * 64;
    short8 a0 = *(const short8*)&qrow[quad * 8];
    short8 a1 = *(const short8*)&qrow[32 + quad * 8];
    f32x4 acc[16] = {};
#pragma unroll
    for (int ni = 0; ni < 16; ni++) {
        short8 b0v = *(const short8*)&KP[(ni * 16 + col) * 72 + quad * 8];
        short8 b1v = *(const short8*)&KP[(ni * 16 + col) * 72 + 32 + quad * 8];
        acc[ni] = mfma_bf16(a0, b0v, acc[ni]);
        acc[ni] = mfma_bf16(a1, b1v, acc[ni]);
    }
    // epilogue: logits = acc*scale + rpe bias
    int mbase = m0 + mw;
    int my = mbase >> 5;
    int mxq = (mbase & 31) + quad * 4;
#pragma unroll
    for (int ni = 0; ni < 16; ni++) {
        int s = ni * 16 + col;
        int p = mxq + sIX[s];
        int iy0 = my + sIY[s];
        float4 w4 = sW4[s];
        int ry0 = ((unsigned)iy0 < 63u) ? (iy0 << 6) : (63 << 6);
        int ry1 = ((unsigned)(iy0 + 1) < 63u) ? ((iy0 + 1) << 6) : (63 << 6);
        float t0[5], t1[5];
#pragma unroll
        for (int jj = 0; jj < 5; jj++) {
            int pj = p + jj;
            int cx = ((unsigned)pj < 63u) ? pj : 63;
            t0[jj] = bf2f(Tb[ry0 + cx]);
            t1[jj] = bf2f(Tb[ry1 + cx]);
        }
#pragma unroll
        for (int r = 0; r < 4; r++) {
            float bias = w4.x * t0[r] + w4.y * t0[r + 1] + w4.z * t1[r] + w4.w * t1[r + 1];
            acc[ni][r] = sat(acc[ni][r] * 0.125f + bias, 64.f);
        }
    }
    // in-register softmax within 16-lane groups
    float rinv_[4];
#pragma unroll
    for (int r = 0; r < 4; r++) {
        float mr = acc[0][r];
#pragma unroll
        for (int ni = 1; ni < 16; ni++) mr = fmaxf(mr, acc[ni][r]);
#pragma unroll
        for (int off = 1; off < 16; off <<= 1) mr = fmaxf(mr, __shfl_xor(mr, off));
        float sr = 0.f;
#pragma unroll
        for (int ni = 0; ni < 16; ni++) {
            float e = __expf(acc[ni][r] - mr);
            acc[ni][r] = e;
            sr += e;
        }
#pragma unroll
        for (int off = 1; off < 16; off <<= 1) sr += __shfl_xor(sr, off);
        rinv_[r] = 1.f / sr;
    }
    __syncthreads();  // all waves done reading Ks; now safe to overwrite with P
#pragma unroll
    for (int ni = 0; ni < 16; ni++)
#pragma unroll
        for (int r = 0; r < 4; r++)
            KP[(mw + quad * 4 + r) * 264 + ni * 16 + col] = f2bf(acc[ni][r]);
    __syncthreads();
    // PV: A from LDS P, B (v) from global
    f32x4 acc2[4] = {};
    const ushort* vp = vS + ((size_t)bl * 512 + h * 64) * 256;
#pragma unroll
    for (int ks = 0; ks < 8; ks++) {
        short8 a = *(const short8*)&KP[(mw + col) * 264 + ks * 32 + quad * 8];
#pragma unroll
        for (int ni = 0; ni < 4; ni++) {
            short8 bb = *(const short8*)&vp[(size_t)(ni * 16 + col) * 256 + ks * 32 + quad * 8];
            acc2[ni] = mfma_bf16(a, bb, acc2[ni]);
        }
    }
#pragma unroll
    for (int ni = 0; ni < 4; ni++)
#pragma unroll
        for (int r = 0; r < 4; r++) {
            int ml = mw + quad * 4 + r;
            float val = sat(acc2[ni][r] * rinv_[r], 64.f);
            outT[((size_t)bl * 1024 + m0 + ml) * 512 + h * 64 + ni * 16 + col] = f2bf(val);
        }
}

// ---------------------------------------------------------------------------
extern "C" void kernel_launch(void* const* d_in, const int* in_sizes, int n_in,
                              void* d_out, int out_size, void* d_ws, size_t ws_size,
                              hipStream_t stream) {
    const float* x   = (const float*)d_in[0];
    const float* Wq  = (const float*)d_in[1];
    const float* bq  = (const float*)d_in[2];
    const float* Wk  = (const float*)d_in[3];
    const float* bk  = (const float*)d_in[4];
    const float* Wv  = (const float*)d_in[5];
    const float* bv  = (const float*)d_in[6];
    const float* Wo  = (const float*)d_in[7];
    const float* bo  = (const float*)d_in[8];
    const float* dww = (const float*)d_in[9];
    const float* dwb = (const float*)d_in[10];
    const float* lng = (const float*)d_in[11];
    const float* lnb = (const float*)d_in[12];
    const float* pww = (const float*)d_in[13];
    const float* rpe = (const float*)d_in[14];
    float* out = (float*)d_out;

    char* wsb = (char*)d_ws;
    size_t off = 256;
    const size_t Wbf_bytes = (size_t)4 * 262144 * 2;   // 2 MB
    const size_t tb8_bytes = (size_t)8 * 4096 * 2;     // 64 KB
    ushort* Wbf = (ushort*)(wsb + off); off += Wbf_bytes;
    ushort* tb8 = (ushort*)(wsb + off); off += tb8_bytes;
    size_t base = (off + 255) & ~(size_t)255;

    const size_t xbT_b = (size_t)1024 * 512 * 2;   // 1 MB
    const size_t qT_b  = (size_t)1024 * 512 * 2;   // 1 MB
    const size_t xsT_b = (size_t)256 * 512 * 2;    // 256 KB
    const size_t kT_b  = (size_t)256 * 512 * 2;    // 256 KB
    const size_t vS_b  = (size_t)512 * 256 * 2;    // 256 KB
    const size_t oT_b  = (size_t)1024 * 512 * 2;   // 1 MB
    const size_t pos_b = (size_t)4 * 256 * 2 * 4;  // 8 KB
    const size_t per_b = xbT_b + qT_b + xsT_b + kT_b + vS_b + oT_b + pos_b + 1024;
    long long avail = (long long)ws_size - (long long)base;
    int bc_cap = (int)(avail > 0 ? avail / (long long)per_b : 0);
    if (bc_cap < 1) bc_cap = 1;
    if (bc_cap > 16) bc_cap = 16;

    prep_w<<<dim3(256, 4), 256, 0, stream>>>(Wq, Wk, Wv, Wo, Wbf);
    prep_rpe<<<8, 256, 0, stream>>>(rpe, tb8);
    const ushort* Wqb = Wbf;
    const ushort* Wkb = Wbf + 262144;
    const ushort* Wvb = Wbf + 2 * 262144;
    const ushort* Wob = Wbf + 3 * 262144;

    for (int b0 = 0; b0 < 16; b0 += bc_cap) {
        int bc = 16 - b0 < bc_cap ? 16 - b0 : bc_cap;
        char* p = wsb + base;
        ushort* xbT  = (ushort*)p; p += xbT_b * bc;
        ushort* qT   = (ushort*)p; p += qT_b * bc;
        ushort* xsT  = (ushort*)p; p += xsT_b * bc;
        ushort* kT   = (ushort*)p; p += kT_b * bc;
        ushort* vS   = (ushort*)p; p += vS_b * bc;
        ushort* outT = (ushort*)p; p += oT_b * bc;
        float*  pos  = (float*)p;

        prep_xT<<<dim3(32, 8, bc), 256, 0, stream>>>(x, xbT, b0);
        gemm_tn<1, 1><<<dim3(16, 8, bc), 256, 0, stream>>>(Wqb, xbT, bq, qT, 512,
                                                           (size_t)1024 * 512, (size_t)1024 * 512, 512, 0);
        offset_net<<<dim3(256, 4 * bc), 128, 0, stream>>>(qT, dww, dwb, lng, lnb, pww,
                                                          pos, out, b0);
        sample_x<<<dim3(256, 4 * bc), 128, 0, stream>>>(x, pos, xsT, b0);
        gemm_tn<1, 1><<<dim3(4, 8, bc), 256, 0, stream>>>(Wkb, xsT, bk, kT, 512,
                                                          (size_t)256 * 512, (size_t)256 * 512, 512, 0);
        gemm_tn<0, 1><<<dim3(4, 8, bc), 256, 0, stream>>>(Wvb, xsT, bv, vS, 512,
                                                          (size_t)256 * 512, (size_t)512 * 256, 256, 0);
        fused_attn<<<dim3(16, 8 * bc), 256, 0, stream>>>(qT, kT, vS, tb8, pos, outT);
        gemm_tn<0, 0><<<dim3(16, 8, bc), 256, 0, stream>>>(Wob, outT, bo, d_out, 512,
                                                           (size_t)1024 * 512, (size_t)512 * 1024, 1024,
                                                           (size_t)b0 * 512 * 1024);
    }
}